// Round 1
// baseline (211.356 us; speedup 1.0000x reference)
//
#include <hip/hip_runtime.h>

// Problem constants (fixed by reference: N=65536, P=512, D=256, fp32 in, fp32 scalar out)
#define NTOT 65536
#define PTOT 512
#define DTOT 256
#define BM   128                 // rows per block
#define BK   32                  // k-chunk
#define NK   (DTOT / BK)         // 8
#define GRID_MAIN (NTOT / BM)    // 512
#define EPSQ 1e-12f

typedef _Float16 f16x8 __attribute__((ext_vector_type(8)));
typedef _Float16 f16x4 __attribute__((ext_vector_type(4)));
typedef float    f32x4 __attribute__((ext_vector_type(4)));

// ---- ws layout (bytes) ----
// [0, 262144)            protosH : 512*256 fp16
// [262144, 264192)       p2      : 512 f32 (from fp16-rounded protos)
// [264192, 1312768)      colpart : 512 blocks * 512 f32 (per-block col sq-mins)
// [1312768, 1314816)     rowpart : 512 f32 (per-block sum of sqrt(row sq-min))
#define WS_P2      262144
#define WS_COLPART 264192
#define WS_ROWPART 1312768

__device__ __forceinline__ void gload_lds16(const void* g, void* l) {
  __builtin_amdgcn_global_load_lds((const __attribute__((address_space(1))) void*)g,
                                   (__attribute__((address_space(3))) void*)l,
                                   16, 0, 0);
}

__device__ __forceinline__ f16x8 cvt8(const float4 a, const float4 b, float& zsq) {
  f16x8 h;
  h[0] = (_Float16)a.x; h[1] = (_Float16)a.y; h[2] = (_Float16)a.z; h[3] = (_Float16)a.w;
  h[4] = (_Float16)b.x; h[5] = (_Float16)b.y; h[6] = (_Float16)b.z; h[7] = (_Float16)b.w;
#pragma unroll
  for (int i = 0; i < 8; ++i) { float f = (float)h[i]; zsq = fmaf(f, f, zsq); }
  return h;
}

// ---------------- pre-pass: protos fp32 -> fp16 + p2 ----------------
__global__ __launch_bounds__(64) void proto_prep_k(const float* __restrict__ protos,
                                                   _Float16* __restrict__ protosH,
                                                   float* __restrict__ p2) {
  const int p = blockIdx.x;   // 512 blocks
  const int l = threadIdx.x;  // 64 threads; 4 floats each
  const float4 v = *reinterpret_cast<const float4*>(protos + (size_t)p * DTOT + l * 4);
  f16x4 h;
  h[0] = (_Float16)v.x; h[1] = (_Float16)v.y; h[2] = (_Float16)v.z; h[3] = (_Float16)v.w;
  *reinterpret_cast<f16x4*>(protosH + (size_t)p * DTOT + l * 4) = h;
  float s = 0.f;
#pragma unroll
  for (int i = 0; i < 4; ++i) { float f = (float)h[i]; s = fmaf(f, f, s); }
#pragma unroll
  for (int m = 1; m < 64; m <<= 1) s += __shfl_xor(s, m, 64);
  if (l == 0) p2[p] = s;
}

// ---------------- main: 128 rows x 512 cols per block, f16 MFMA ----------------
__global__ __launch_bounds__(512, 2) void pdist_main_k(const float* __restrict__ z,
                                                       const _Float16* __restrict__ protosH,
                                                       const float* __restrict__ p2g,
                                                       float* __restrict__ colpart,
                                                       float* __restrict__ rowpart) {
  __shared__ _Float16 Plds[2][PTOT * BK];   // 64 KB
  __shared__ _Float16 Zlds[2][BM * BK];     // 16 KB
  __shared__ float p2s[PTOT];               // 2 KB
  __shared__ float zsqs[BM];                // 0.5 KB
  __shared__ float rowmin_s[4][BM];         // 2 KB
  __shared__ float colmin_s[2][PTOT];       // 4 KB
  __shared__ float rsum_s[2];

  const int t    = threadIdx.x;
  const int lane = t & 63;
  const int wid  = t >> 6;   // 0..7
  const int wr   = wid >> 2; // row half 0..1 (64 rows each)
  const int wc   = wid & 3;  // col strip 0..3 (128 cols each)
  const int bid  = blockIdx.x;

  p2s[t] = p2g[t];           // t < 512 == PTOT

  // staging geometry: z reg-staged (fp32->fp16), protos via global_load_lds
  const int srow = t >> 2;   // 0..127
  const int sg   = t & 3;    // 8-float chunk within 32-float k-chunk
  const float* zsrc = z + (size_t)(bid * BM + srow) * DTOT + sg * 8;
  _Float16* zdst0 = &Zlds[0][srow * BK + sg * 8];
  _Float16* zdst1 = &Zlds[1][srow * BK + sg * 8];
  // proto staging: wave wid covers cols [wid*64, wid*64+64), 4 calls of 1KB
  const _Float16* psrc = protosH + (size_t)(wid * 64 + (lane >> 2)) * DTOT + (lane & 3) * 8;

  float zsq = 0.f;

  f32x4 acc[4][8];
#pragma unroll
  for (int a = 0; a < 4; ++a)
#pragma unroll
    for (int b = 0; b < 8; ++b) acc[a][b] = (f32x4)0.f;

  // prologue: stage k-chunk 0 into buffer 0
  {
    float4 va = *reinterpret_cast<const float4*>(zsrc);
    float4 vb = *reinterpret_cast<const float4*>(zsrc + 4);
#pragma unroll
    for (int j = 0; j < 4; ++j)
      gload_lds16(psrc + j * 16 * DTOT,
                  reinterpret_cast<char*>(&Plds[0][0]) + wid * 4096 + j * 1024);
    f16x8 h = cvt8(va, vb, zsq);
    *reinterpret_cast<f16x8*>(zdst0) = h;
  }
  __syncthreads();

  const int fr = lane & 15;  // fragment free index
  const int fg = lane >> 4;  // k-group
  int cur = 0;
  for (int kb = 0; kb < NK; ++kb) {
    float4 va, vb;
    if (kb + 1 < NK) {
      // issue next z loads early (latency hides under MFMA cluster)
      va = *reinterpret_cast<const float4*>(zsrc + (kb + 1) * BK);
      vb = *reinterpret_cast<const float4*>(zsrc + (kb + 1) * BK + 4);
      // issue next proto tile direct-to-LDS
#pragma unroll
      for (int j = 0; j < 4; ++j)
        gload_lds16(psrc + j * 16 * DTOT + (kb + 1) * BK,
                    reinterpret_cast<char*>(&Plds[cur ^ 1][0]) + wid * 4096 + j * 1024);
    }

    f16x8 afrag[4], bfrag[8];
#pragma unroll
    for (int rf = 0; rf < 4; ++rf)
      afrag[rf] = *reinterpret_cast<const f16x8*>(
          &Zlds[cur][(wr * 64 + rf * 16 + fr) * BK + fg * 8]);
#pragma unroll
    for (int cf = 0; cf < 8; ++cf)
      bfrag[cf] = *reinterpret_cast<const f16x8*>(
          &Plds[cur][(wc * 128 + cf * 16 + fr) * BK + fg * 8]);
#pragma unroll
    for (int rf = 0; rf < 4; ++rf)
#pragma unroll
      for (int cf = 0; cf < 8; ++cf)
        acc[rf][cf] = __builtin_amdgcn_mfma_f32_16x16x32_f16(afrag[rf], bfrag[cf],
                                                             acc[rf][cf], 0, 0, 0);

    if (kb + 1 < NK) {
      f16x8 h = cvt8(va, vb, zsq);
      *reinterpret_cast<f16x8*>(cur ? zdst0 : zdst1) = h;  // write buf cur^1
    }
    __syncthreads();
    cur ^= 1;
  }

  // finish z row sums-of-squares: combine the 4 staging lanes of each row
  zsq += __shfl_xor(zsq, 1, 64);
  zsq += __shfl_xor(zsq, 2, 64);
  if (sg == 0) zsqs[srow] = zsq;
  __syncthreads();

  // epilogue: sq = z2 + p2 - 2*dot, clamp, row/col mins (sqrt deferred: monotonic)
  float p2l[8];
#pragma unroll
  for (int cf = 0; cf < 8; ++cf) p2l[cf] = p2s[wc * 128 + cf * 16 + fr];
  float zl[4][4];
#pragma unroll
  for (int rf = 0; rf < 4; ++rf)
#pragma unroll
    for (int r = 0; r < 4; ++r) zl[rf][r] = zsqs[wr * 64 + rf * 16 + fg * 4 + r];

  float rowm[4][4], colm[8];
#pragma unroll
  for (int rf = 0; rf < 4; ++rf)
#pragma unroll
    for (int r = 0; r < 4; ++r) rowm[rf][r] = 3.4e38f;
#pragma unroll
  for (int cf = 0; cf < 8; ++cf) colm[cf] = 3.4e38f;

#pragma unroll
  for (int rf = 0; rf < 4; ++rf)
#pragma unroll
    for (int cf = 0; cf < 8; ++cf) {
      f32x4 a = acc[rf][cf];
#pragma unroll
      for (int r = 0; r < 4; ++r) {
        float sq = fmaxf(zl[rf][r] + p2l[cf] - 2.f * a[r], EPSQ);
        rowm[rf][r] = fminf(rowm[rf][r], sq);
        colm[cf]    = fminf(colm[cf], sq);
      }
    }

  // row-min across the 16 lanes sharing a row (lane&15 dimension)
#pragma unroll
  for (int m = 1; m <= 8; m <<= 1)
#pragma unroll
    for (int rf = 0; rf < 4; ++rf)
#pragma unroll
      for (int r = 0; r < 4; ++r)
        rowm[rf][r] = fminf(rowm[rf][r], __shfl_xor(rowm[rf][r], m, 64));
  if (fr == 0)
#pragma unroll
    for (int rf = 0; rf < 4; ++rf)
#pragma unroll
      for (int r = 0; r < 4; ++r)
        rowmin_s[wc][wr * 64 + rf * 16 + fg * 4 + r] = rowm[rf][r];

  // col-min across the 4 k-groups (lane>>4 dimension)
#pragma unroll
  for (int m = 16; m <= 32; m <<= 1)
#pragma unroll
    for (int cf = 0; cf < 8; ++cf)
      colm[cf] = fminf(colm[cf], __shfl_xor(colm[cf], m, 64));
  if (lane < 16)
#pragma unroll
    for (int cf = 0; cf < 8; ++cf)
      colmin_s[wr][wc * 128 + cf * 16 + fr] = colm[cf];
  __syncthreads();

  // block finalize
  if (t < BM) {  // waves 0,1 fully active -> shfl safe
    float m = fminf(fminf(rowmin_s[0][t], rowmin_s[1][t]),
                    fminf(rowmin_s[2][t], rowmin_s[3][t]));
    float d = sqrtf(m);
#pragma unroll
    for (int mm = 1; mm < 64; mm <<= 1) d += __shfl_xor(d, mm, 64);
    if (lane == 0) rsum_s[t >> 6] = d;
  }
  {
    float c = fminf(colmin_s[0][t], colmin_s[1][t]);
    colpart[(size_t)bid * PTOT + t] = c;   // store sq-min; sqrt in final kernel
  }
  __syncthreads();
  if (t == 0) rowpart[bid] = rsum_s[0] + rsum_s[1];
}

// ---------------- final: combine 512 block partials ----------------
__global__ __launch_bounds__(512) void pdist_final_k(const float* __restrict__ colpart,
                                                     const float* __restrict__ rowpart,
                                                     float* __restrict__ out) {
  const int t = threadIdx.x, lane = t & 63, wid = t >> 6;
  float m = 3.4e38f;
  for (int b = 0; b < GRID_MAIN; ++b) m = fminf(m, colpart[(size_t)b * PTOT + t]);
  float fs = sqrtf(m);
  float ps = rowpart[t];  // GRID_MAIN == 512 == blockDim
#pragma unroll
  for (int mm = 1; mm < 64; mm <<= 1) {
    fs += __shfl_xor(fs, mm, 64);
    ps += __shfl_xor(ps, mm, 64);
  }
  __shared__ float red[2][8];
  if (lane == 0) { red[0][wid] = fs; red[1][wid] = ps; }
  __syncthreads();
  if (t == 0) {
    float F = 0.f, P = 0.f;
#pragma unroll
    for (int w = 0; w < 8; ++w) { F += red[0][w]; P += red[1][w]; }
    out[0] = 0.05f * (P / (float)NTOT) + 0.05f * (F / (float)PTOT);
  }
}

extern "C" void kernel_launch(void* const* d_in, const int* in_sizes, int n_in,
                              void* d_out, int out_size, void* d_ws, size_t ws_size,
                              hipStream_t stream) {
  const float* z      = (const float*)d_in[0];  // [65536,256] f32
  const float* protos = (const float*)d_in[1];  // [512,256] f32
  float* out = (float*)d_out;                   // scalar f32

  char* ws = (char*)d_ws;                       // needs ~1.26 MB
  _Float16* protosH = (_Float16*)ws;
  float* p2      = (float*)(ws + WS_P2);
  float* colpart = (float*)(ws + WS_COLPART);
  float* rowpart = (float*)(ws + WS_ROWPART);

  proto_prep_k<<<PTOT, 64, 0, stream>>>(protos, protosH, p2);
  pdist_main_k<<<GRID_MAIN, 512, 0, stream>>>(z, protosH, p2, colpart, rowpart);
  pdist_final_k<<<1, 512, 0, stream>>>(colpart, rowpart, out);
}

// Round 4
// 131.716 us; speedup vs baseline: 1.6046x; 1.6046x over previous
//
#include <hip/hip_runtime.h>

// N=65536, P=512, D=256, fp32 in, fp32 scalar out
#define NTOT 65536
#define PTOT 512
#define DTOT 256
#define BM   64                  // rows per block
#define BK   32                  // k-chunk
#define NK   (DTOT / BK)         // 8
#define GRID_MAIN (NTOT / BM)    // 1024
#define EPSQ 1e-12f

typedef _Float16 f16x8 __attribute__((ext_vector_type(8)));
typedef _Float16 f16x4 __attribute__((ext_vector_type(4)));
typedef float    f32x4 __attribute__((ext_vector_type(4)));

// ---- ws layout (bytes) ----
#define WS_P2      262144            // 512 f32
#define WS_COLPART 264192            // 1024 * 512 f32 (per-block col sq-mins)
#define WS_ROWPART 2361344           // 1024 f32 (per-block sum of sqrt(row sq-min))
#define WS_FMINSQ  2365440           // 512 f32 (global col sq-mins)

__device__ __forceinline__ void gload_lds16(const void* g, void* l) {
  __builtin_amdgcn_global_load_lds((const __attribute__((address_space(1))) void*)g,
                                   (__attribute__((address_space(3))) void*)l,
                                   16, 0, 0);
}

__device__ __forceinline__ f16x8 cvt8(const float4 a, const float4 b, float& zsq) {
  f16x8 h;
  h[0] = (_Float16)a.x; h[1] = (_Float16)a.y; h[2] = (_Float16)a.z; h[3] = (_Float16)a.w;
  h[4] = (_Float16)b.x; h[5] = (_Float16)b.y; h[6] = (_Float16)b.z; h[7] = (_Float16)b.w;
#pragma unroll
  for (int i = 0; i < 8; ++i) { float f = (float)h[i]; zsq = fmaf(f, f, zsq); }
  return h;
}

// ---------------- pre-pass: protos fp32 -> fp16 + p2 ----------------
__global__ __launch_bounds__(64) void proto_prep_k(const float* __restrict__ protos,
                                                   _Float16* __restrict__ protosH,
                                                   float* __restrict__ p2) {
  const int p = blockIdx.x;   // 512 blocks
  const int l = threadIdx.x;  // 64 threads; 4 floats each
  const float4 v = *reinterpret_cast<const float4*>(protos + (size_t)p * DTOT + l * 4);
  f16x4 h;
  h[0] = (_Float16)v.x; h[1] = (_Float16)v.y; h[2] = (_Float16)v.z; h[3] = (_Float16)v.w;
  *reinterpret_cast<f16x4*>(protosH + (size_t)p * DTOT + l * 4) = h;
  float s = 0.f;
#pragma unroll
  for (int i = 0; i < 4; ++i) { float f = (float)h[i]; s = fmaf(f, f, s); }
#pragma unroll
  for (int m = 1; m < 64; m <<= 1) s += __shfl_xor(s, m, 64);
  if (l == 0) p2[p] = s;
}

// ---------------- main: 64 rows x 512 cols per block, 4 waves, f16 MFMA ----------------
// LDS: 64 (P dbuf) + 8 (Z dbuf) + ~1.3 KB misc = ~73 KB  -> 2 blocks/CU.
__global__ __launch_bounds__(256, 2) void pdist_main_k(const float* __restrict__ z,
                                                       const _Float16* __restrict__ protosH,
                                                       const float* __restrict__ p2g,
                                                       float* __restrict__ colpart,
                                                       float* __restrict__ rowpart) {
  __shared__ _Float16 Plds[2][PTOT * BK];   // 64 KB
  __shared__ _Float16 Zlds[2][BM * BK];     // 8 KB
  __shared__ float zsqs[BM];                // 256 B
  __shared__ float rowmin_s[4][BM];         // 1 KB

  const int t    = threadIdx.x;
  const int lane = t & 63;
  const int wid  = t >> 6;   // 0..3 : col strip (128 cols each)
  const int bid  = blockIdx.x;

  // staging geometry
  const int srow = t >> 2;   // 0..63
  const int sg   = t & 3;    // 8-float chunk within 32-float k-chunk
  const float* zsrc = z + (size_t)(bid * BM + srow) * DTOT + sg * 8;
  // proto staging: wave wid stages rows [wid*128, wid*128+128), 8 calls x 1KB (16 rows each)
  const _Float16* psrc = protosH + (size_t)(wid * 128 + (lane >> 2)) * DTOT + (lane & 3) * 8;
  char* pldsb0 = reinterpret_cast<char*>(&Plds[0][0]) + wid * 8192;
  char* pldsb1 = reinterpret_cast<char*>(&Plds[1][0]) + wid * 8192;

  float zsq = 0.f;

  f32x4 acc[4][8];
#pragma unroll
  for (int a = 0; a < 4; ++a)
#pragma unroll
    for (int b = 0; b < 8; ++b) acc[a][b] = (f32x4)0.f;

  // prologue: stage k-chunk 0 into buffer 0
  {
    float4 va = *reinterpret_cast<const float4*>(zsrc);
    float4 vb = *reinterpret_cast<const float4*>(zsrc + 4);
#pragma unroll
    for (int j = 0; j < 8; ++j)
      gload_lds16(psrc + j * 16 * DTOT, pldsb0 + j * 1024);
    f16x8 h = cvt8(va, vb, zsq);
    *reinterpret_cast<f16x8*>(&Zlds[0][srow * BK + sg * 8]) = h;
  }
  __syncthreads();

  const int fr = lane & 15;  // fragment free index
  const int fg = lane >> 4;  // k-group
#pragma unroll
  for (int kb = 0; kb < NK; ++kb) {
    const int cur = kb & 1;
    float4 va, vb;
    if (kb + 1 < NK) {
      va = *reinterpret_cast<const float4*>(zsrc + (kb + 1) * BK);
      vb = *reinterpret_cast<const float4*>(zsrc + (kb + 1) * BK + 4);
#pragma unroll
      for (int j = 0; j < 8; ++j)
        gload_lds16(psrc + j * 16 * DTOT + (kb + 1) * BK,
                    (cur ? pldsb0 : pldsb1) + j * 1024);
    }

    f16x8 afrag[4], bfrag[8];
#pragma unroll
    for (int rf = 0; rf < 4; ++rf)
      afrag[rf] = *reinterpret_cast<const f16x8*>(
          &Zlds[cur][(rf * 16 + fr) * BK + fg * 8]);
#pragma unroll
    for (int cf = 0; cf < 8; ++cf)
      bfrag[cf] = *reinterpret_cast<const f16x8*>(
          &Plds[cur][(wid * 128 + cf * 16 + fr) * BK + fg * 8]);
#pragma unroll
    for (int rf = 0; rf < 4; ++rf)
#pragma unroll
      for (int cf = 0; cf < 8; ++cf)
        acc[rf][cf] = __builtin_amdgcn_mfma_f32_16x16x32_f16(afrag[rf], bfrag[cf],
                                                             acc[rf][cf], 0, 0, 0);

    if (kb + 1 < NK) {
      f16x8 h = cvt8(va, vb, zsq);
      *reinterpret_cast<f16x8*>(&Zlds[cur ^ 1][srow * BK + sg * 8]) = h;
    }
    __syncthreads();
  }

  // z row sums-of-squares: combine the 4 staging lanes of each row
  zsq += __shfl_xor(zsq, 1, 64);
  zsq += __shfl_xor(zsq, 2, 64);
  if (sg == 0) zsqs[srow] = zsq;
  __syncthreads();

  // epilogue: sq = z2 + p2 - 2*dot, clamp, row/col mins (sqrt deferred: monotonic)
  float p2l[8];
#pragma unroll
  for (int cf = 0; cf < 8; ++cf) p2l[cf] = p2g[wid * 128 + cf * 16 + fr];
  float zl[4][4];
#pragma unroll
  for (int rf = 0; rf < 4; ++rf)
#pragma unroll
    for (int r = 0; r < 4; ++r) zl[rf][r] = zsqs[rf * 16 + fg * 4 + r];

  float rowm[4][4], colm[8];
#pragma unroll
  for (int rf = 0; rf < 4; ++rf)
#pragma unroll
    for (int r = 0; r < 4; ++r) rowm[rf][r] = 3.4e38f;
#pragma unroll
  for (int cf = 0; cf < 8; ++cf) colm[cf] = 3.4e38f;

#pragma unroll
  for (int rf = 0; rf < 4; ++rf)
#pragma unroll
    for (int cf = 0; cf < 8; ++cf) {
      f32x4 a = acc[rf][cf];
#pragma unroll
      for (int r = 0; r < 4; ++r) {
        float sq = fmaxf(zl[rf][r] + p2l[cf] - 2.f * a[r], EPSQ);
        rowm[rf][r] = fminf(rowm[rf][r], sq);
        colm[cf]    = fminf(colm[cf], sq);
      }
    }

  // row-min across the 16 lanes sharing a row (fr dimension)
#pragma unroll
  for (int m = 1; m <= 8; m <<= 1)
#pragma unroll
    for (int rf = 0; rf < 4; ++rf)
#pragma unroll
      for (int r = 0; r < 4; ++r)
        rowm[rf][r] = fminf(rowm[rf][r], __shfl_xor(rowm[rf][r], m, 64));
  if (fr == 0)
#pragma unroll
    for (int rf = 0; rf < 4; ++rf)
#pragma unroll
      for (int r = 0; r < 4; ++r)
        rowmin_s[wid][rf * 16 + fg * 4 + r] = rowm[rf][r];

  // col-min across the 4 k-groups (fg dimension); each wave owns distinct cols
#pragma unroll
  for (int m = 16; m <= 32; m <<= 1)
#pragma unroll
    for (int cf = 0; cf < 8; ++cf)
      colm[cf] = fminf(colm[cf], __shfl_xor(colm[cf], m, 64));
  if (fg == 0)
#pragma unroll
    for (int cf = 0; cf < 8; ++cf)
      colpart[(size_t)bid * PTOT + wid * 128 + cf * 16 + fr] = colm[cf];  // sq domain
  __syncthreads();

  if (t < BM) {  // wave 0 fully active -> shfl safe
    float m = fminf(fminf(rowmin_s[0][t], rowmin_s[1][t]),
                    fminf(rowmin_s[2][t], rowmin_s[3][t]));
    float d = sqrtf(m);
#pragma unroll
    for (int mm = 1; mm < 64; mm <<= 1) d += __shfl_xor(d, mm, 64);
    if (t == 0) rowpart[bid] = d;
  }
}

// ---------------- parallel col-min tree: one block per proto column ----------------
__global__ __launch_bounds__(256) void reduce_cols_k(const float* __restrict__ colpart,
                                                     float* __restrict__ fmin_sq) {
  const int p = blockIdx.x;           // 512 blocks
  const int t = threadIdx.x;          // 256 threads
  float m = 3.4e38f;
#pragma unroll
  for (int j = 0; j < 4; ++j)
    m = fminf(m, colpart[(size_t)(j * 256 + t) * PTOT + p]);
#pragma unroll
  for (int mm = 1; mm < 64; mm <<= 1) m = fminf(m, __shfl_xor(m, mm, 64));
  __shared__ float red[4];
  if ((t & 63) == 0) red[t >> 6] = m;
  __syncthreads();
  if (t == 0)
    fmin_sq[p] = fminf(fminf(red[0], red[1]), fminf(red[2], red[3]));
}

// ---------------- finalize: 512 col-mins + 1024 row partial sums -> scalar ----------------
__global__ __launch_bounds__(512) void finalize_k(const float* __restrict__ fmin_sq,
                                                  const float* __restrict__ rowpart,
                                                  float* __restrict__ out) {
  const int t = threadIdx.x, lane = t & 63, wid = t >> 6;
  float fs = sqrtf(fmin_sq[t]);                 // t < 512
  float ps = rowpart[t] + rowpart[t + 512];     // 1024 entries
#pragma unroll
  for (int mm = 1; mm < 64; mm <<= 1) {
    fs += __shfl_xor(fs, mm, 64);
    ps += __shfl_xor(ps, mm, 64);
  }
  __shared__ float red[2][8];
  if (lane == 0) { red[0][wid] = fs; red[1][wid] = ps; }
  __syncthreads();
  if (t == 0) {
    float F = 0.f, P = 0.f;
#pragma unroll
    for (int w = 0; w < 8; ++w) { F += red[0][w]; P += red[1][w]; }
    out[0] = 0.05f * (P / (float)NTOT) + 0.05f * (F / (float)PTOT);
  }
}

extern "C" void kernel_launch(void* const* d_in, const int* in_sizes, int n_in,
                              void* d_out, int out_size, void* d_ws, size_t ws_size,
                              hipStream_t stream) {
  const float* z      = (const float*)d_in[0];  // [65536,256] f32
  const float* protos = (const float*)d_in[1];  // [512,256] f32
  float* out = (float*)d_out;                   // scalar f32

  char* ws = (char*)d_ws;                       // needs ~2.27 MB
  _Float16* protosH = (_Float16*)ws;
  float* p2      = (float*)(ws + WS_P2);
  float* colpart = (float*)(ws + WS_COLPART);
  float* rowpart = (float*)(ws + WS_ROWPART);
  float* fmin_sq = (float*)(ws + WS_FMINSQ);

  proto_prep_k<<<PTOT, 64, 0, stream>>>(protos, protosH, p2);
  pdist_main_k<<<GRID_MAIN, 256, 0, stream>>>(z, protosH, p2, colpart, rowpart);
  reduce_cols_k<<<PTOT, 256, 0, stream>>>(colpart, fmin_sq);
  finalize_k<<<1, 512, 0, stream>>>(fmin_sq, rowpart, out);
}